// Round 3
// baseline (14479.942 us; speedup 1.0000x reference)
//
#include <hip/hip_runtime.h>

#define B_  4096
#define T_  2048
#define H1_ 32
#define H2_ 16
#define RPB 4   // independent rows (waves) per 256-thread block

#define LOG2E     1.44269504088896340736f
#define TWOLOG2E  2.88539008177792681472f

// All gate pre-activations are computed directly in the exp2 domain:
// weights/biases pre-scaled by log2(e) (sigmoid rows) or 2*log2(e) (tanh rows).
//   sigmoid: rcp(1 + exp2(-z))
//   tanh:    fma(2, rcp(1 + exp2(-z)), -1)      [z = 2*log2e*d]
// h1/h2 are wave-uniform -> broadcast via v_readlane into SGPRs; every gate FMA
// reads the h operand from the SGPR (1 SGPR src per VALU op is legal).

__device__ __forceinline__ float lane_bcast(float v, int srcLane) {
    return __uint_as_float(__builtin_amdgcn_readlane(__float_as_uint(v), srcLane));
}
__device__ __forceinline__ float uni(float v) {
    return __uint_as_float(__builtin_amdgcn_readfirstlane(__float_as_uint(v)));
}

__global__ __launch_bounds__(64 * RPB, 3) void lstm_deep_kernel(
    const float* __restrict__ x,
    const float* __restrict__ W_ih1,
    const float* __restrict__ W_hh1,
    const float* __restrict__ b_ih1,
    const float* __restrict__ b_hh1,
    const float* __restrict__ W_ih2,
    const float* __restrict__ W_hh2,
    const float* __restrict__ b_ih2,
    const float* __restrict__ b_hh2,
    const float* __restrict__ W_out,
    const float* __restrict__ b_out,
    float* __restrict__ out)
{
    const int tid  = threadIdx.x;
    const int lane = tid & 63;
    const int wid  = __builtin_amdgcn_readfirstlane(tid >> 6);  // wave id, uniform
    const int row  = blockIdx.x * RPB + wid;

    // ---- per-lane weights (pre-scaled), pinned into VGPRs ----
    const bool  low  = (lane < 32);
    const int   ga   = lane;        // layer1: i (low) / f (high) rows
    const int   gb   = 64 + lane;   // layer1: g (low) / o (high) rows
    const float scb1 = low ? TWOLOG2E : LOG2E;   // g is tanh -> 2*log2e

    float w1a[H1_], w1b[H1_];
    #pragma unroll
    for (int k = 0; k < H1_; ++k) {
        w1a[k] = W_hh1[ga * H1_ + k] * LOG2E;
        w1b[k] = W_hh1[gb * H1_ + k] * scb1;
    }
    float wxa = W_ih1[ga] * LOG2E;
    float wxb = W_ih1[gb] * scb1;
    float ba  = (b_ih1[ga] + b_hh1[ga]) * LOG2E;
    float bb  = (b_ih1[gb] + b_hh1[gb]) * scb1;

    const int   gt   = lane >> 4;                 // layer2 gate: 0=i 1=f 2=g 3=o
    const float sc2w = (gt == 2) ? TWOLOG2E : LOG2E;
    float w2a[H1_];
    #pragma unroll
    for (int k = 0; k < H1_; ++k) w2a[k] = W_ih2[lane * H1_ + k] * sc2w;
    float w2b[H2_];
    #pragma unroll
    for (int k = 0; k < H2_; ++k) w2b[k] = W_hh2[lane * H2_ + k] * sc2w;
    float b2 = (b_ih2[lane] + b_hh2[lane]) * sc2w;

    // opaque pin: forbid rematerialization-by-reload inside the loop
    #pragma unroll
    for (int k = 0; k < H1_; ++k)
        asm volatile("" : "+v"(w1a[k]), "+v"(w1b[k]), "+v"(w2a[k]));
    #pragma unroll
    for (int k = 0; k < H2_; ++k)
        asm volatile("" : "+v"(w2b[k]));
    asm volatile("" : "+v"(wxa), "+v"(wxb));
    asm volatile("" : "+v"(ba), "+v"(bb), "+v"(b2));

    // activation combine constants: act = fma(sc, sigmoid_core, of)
    const float sc1b = low ? 2.0f : 1.0f;
    const float of1b = low ? -1.0f : 0.0f;
    const float sc2c = (gt == 2) ? 2.0f : 1.0f;
    const float of2c = (gt == 2) ? -1.0f : 0.0f;

    const int   u2   = lane & 15;
    const float wout = W_out[u2];
    const float bout = uni(b_out[0]);

    // ---- wave-uniform state (SGPRs) + per-lane cells ----
    float sh1[H1_], sh2[H2_];
    #pragma unroll
    for (int k = 0; k < H1_; ++k) sh1[k] = 0.0f;
    #pragma unroll
    for (int k = 0; k < H2_; ++k) sh2[k] = 0.0f;
    float c1 = 0.0f;   // valid in high lanes (unit = lane-32)
    float c2 = 0.0f;   // replicated x4 (unit = lane&15)

    const float4* __restrict__ xr4  = reinterpret_cast<const float4*>(x + (size_t)row * T_);
    float*        __restrict__ orow = out + (size_t)row * T_;

    auto step = [&](float xt) -> float {
        // ---- layer 1: two gate rows per lane, SGPR h operands ----
        float acca = __builtin_fmaf(wxa, xt, ba);
        float accb = __builtin_fmaf(wxb, xt, bb);
        #pragma unroll
        for (int k = 0; k < H1_; ++k) {
            acca = __builtin_fmaf(w1a[k], sh1[k], acca);
            accb = __builtin_fmaf(w1b[k], sh1[k], accb);
        }
        const float sa = __builtin_amdgcn_rcpf(1.0f + __builtin_amdgcn_exp2f(-acca));
        const float sb = __builtin_fmaf(
            sc1b, __builtin_amdgcn_rcpf(1.0f + __builtin_amdgcn_exp2f(-accb)), of1b);
        const float pv = __shfl_xor(sa * sb, 32);   // high lanes get sig(i)*tanh(g)
        c1 = __builtin_fmaf(sa, c1, pv);            // high: sig(f)*c1 + p
        const float tc1 = __builtin_fmaf(
            2.0f, __builtin_amdgcn_rcpf(1.0f + __builtin_amdgcn_exp2f(c1 * -TWOLOG2E)), -1.0f);
        const float h1new = sb * tc1;               // valid in lanes 32..63

        #pragma unroll
        for (int k = 0; k < H1_; ++k) sh1[k] = lane_bcast(h1new, 32 + k);

        // ---- layer 2: one gate row per lane ----
        float e0 = b2, e1 = 0.0f, e2 = 0.0f, e3 = 0.0f;
        #pragma unroll
        for (int k = 0; k < H1_; k += 4) {
            e0 = __builtin_fmaf(w2a[k+0], sh1[k+0], e0);
            e1 = __builtin_fmaf(w2a[k+1], sh1[k+1], e1);
            e2 = __builtin_fmaf(w2a[k+2], sh1[k+2], e2);
            e3 = __builtin_fmaf(w2a[k+3], sh1[k+3], e3);
        }
        #pragma unroll
        for (int k = 0; k < H2_; k += 4) {
            e0 = __builtin_fmaf(w2b[k+0], sh2[k+0], e0);
            e1 = __builtin_fmaf(w2b[k+1], sh2[k+1], e1);
            e2 = __builtin_fmaf(w2b[k+2], sh2[k+2], e2);
            e3 = __builtin_fmaf(w2b[k+3], sh2[k+3], e3);
        }
        const float d2 = (e0 + e1) + (e2 + e3);

        const float s2 = __builtin_fmaf(
            sc2c, __builtin_amdgcn_rcpf(1.0f + __builtin_amdgcn_exp2f(-d2)), of2c);
        const float iv = __shfl(s2, u2);
        const float fv = __shfl(s2, u2 + 16);
        const float gv = __shfl(s2, u2 + 32);
        const float ov = __shfl(s2, u2 + 48);

        c2 = __builtin_fmaf(fv, c2, iv * gv);
        const float tc2 = __builtin_fmaf(
            2.0f, __builtin_amdgcn_rcpf(1.0f + __builtin_amdgcn_exp2f(c2 * -TWOLOG2E)), -1.0f);
        const float h2v = ov * tc2;                 // h2[u2], replicated x4

        #pragma unroll
        for (int k = 0; k < H2_; ++k) sh2[k] = lane_bcast(h2v, k);

        // y = h2 . W_out + b_out (16-lane xor reduce; all lanes end with y)
        float part = wout * h2v;
        part += __shfl_xor(part, 1);
        part += __shfl_xor(part, 2);
        part += __shfl_xor(part, 4);
        part += __shfl_xor(part, 8);
        return part + bout;
    };

    float4 xv = xr4[0];
    #pragma unroll 1
    for (int t4 = 0; t4 < T_ / 4; ++t4) {
        const int nx = (t4 + 1 < T_ / 4) ? (t4 + 1) : t4;
        const float4 xn = xr4[nx];    // prefetch next 4 inputs

        const float y0 = step(xv.x);
        const float y1 = step(xv.y);
        const float y2 = step(xv.z);
        const float y3 = step(xv.w);

        if (lane == 0) {
            *reinterpret_cast<float4*>(orow + 4 * t4) = make_float4(y0, y1, y2, y3);
        }
        xv = xn;
    }
}

extern "C" void kernel_launch(void* const* d_in, const int* in_sizes, int n_in,
                              void* d_out, int out_size, void* d_ws, size_t ws_size,
                              hipStream_t stream) {
    const float* xp     = (const float*)d_in[0];
    const float* W_ih1  = (const float*)d_in[1];
    const float* W_hh1  = (const float*)d_in[2];
    const float* b_ih1  = (const float*)d_in[3];
    const float* b_hh1  = (const float*)d_in[4];
    const float* W_ih2  = (const float*)d_in[5];
    const float* W_hh2  = (const float*)d_in[6];
    const float* b_ih2  = (const float*)d_in[7];
    const float* b_hh2  = (const float*)d_in[8];
    const float* W_out  = (const float*)d_in[9];
    const float* b_out  = (const float*)d_in[10];
    float* out = (float*)d_out;

    dim3 grid(B_ / RPB);
    dim3 block(64 * RPB);
    lstm_deep_kernel<<<grid, block, 0, stream>>>(
        xp, W_ih1, W_hh1, b_ih1, b_hh1, W_ih2, W_hh2, b_ih2, b_hh2, W_out, b_out, out);
}